// Round 7
// baseline (139.506 us; speedup 1.0000x reference)
//
#include <hip/hip_runtime.h>
#include <float.h>

#define K_CODES 1024
#define DIM 64
#define T_LEN 8192
#define N_TOK 131072          // 16 * 8192 tokens
#define LO_SCALE 2048.0f
#define LO_INV   (1.0f / 2048.0f)

typedef _Float16 half8 __attribute__((ext_vector_type(8)));  // 4 VGPRs: MFMA A/B frag
typedef float    f32x4 __attribute__((ext_vector_type(4)));  // MFMA C/D frag

#define MFMA16(a, b, c) __builtin_amdgcn_mfma_f32_16x16x32_f16((a), (b), (c), 0, 0, 0)

typedef __attribute__((address_space(3))) void* as3_void;
typedef const __attribute__((address_space(1))) void* as1_cvoid;

// async global->LDS, 16B per lane; LDS dest = wave-uniform base + lane*16.
__device__ inline void async_16B(const void* g, void* l) {
#if __has_builtin(__builtin_amdgcn_global_load_lds)
    __builtin_amdgcn_global_load_lds((as1_cvoid)g, (as3_void)l, 16, 0, 0);
#else
    *(float4*)l = *(const float4*)g;   // fallback: VGPR round-trip
#endif
}

// ---------------- prep: codebook -> tiled f16 hi/lo + e_sq (unchanged r6) ----------------
// Tile ct (16 codes) = 4 KB contiguous, frag order: hi[q=0..7][code=0..15][j=0..7], lo at +1024.
__global__ void vq_prep(const float* __restrict__ cb,
                        _Float16* __restrict__ w,
                        float* __restrict__ wesq) {
    __shared__ float part[128];
    const int ct   = blockIdx.x;
    const int r    = threadIdx.x;
    const int halF = r >> 7;           // 0: hi chunk, 1: lo chunk
    const int rr   = r & 127;
    const int q    = rr >> 4;          // k-octet
    const int code = rr & 15;

    const float* src = cb + (size_t)(ct * 16 + code) * DIM + q * 8;
    float4 v0 = *reinterpret_cast<const float4*>(src);
    float4 v1 = *reinterpret_cast<const float4*>(src + 4);
    float x[8] = {v0.x, v0.y, v0.z, v0.w, v1.x, v1.y, v1.z, v1.w};

    half8 o;
    float psum = 0.0f;
    #pragma unroll
    for (int j = 0; j < 8; ++j) {
        _Float16 h = (_Float16)x[j];
        o[j] = halF ? (_Float16)((x[j] - (float)h) * LO_SCALE) : h;  // (x-h) exact in fp32
        psum = fmaf(x[j], x[j], psum);
    }
    *reinterpret_cast<half8*>(w + (size_t)ct * 2048 + halF * 1024 + q * 128 + code * 8) = o;

    if (halF == 0) part[rr] = psum;
    __syncthreads();
    if (r < 16) {
        float s = 0.0f;
        #pragma unroll
        for (int q2 = 0; q2 < 8; ++q2) s += part[q2 * 16 + r];
        wesq[ct * 16 + r] = s;
    }
}

// ---------------- main: LDS-staged split-f16 MFMA + fused argmin + gather ----------------
// Block = 4 waves x 32 tokens. All 4 waves consume the SAME B tiles -> stage into LDS
// once per block (L2 traffic /4 vs r6's 1.06 GB). Double buffer, 4 tiles (16 KB) per
// period; prefetch for period p+1 issued BEFORE computing period p, so the barrier's
// vmcnt drain finds loads already complete (~3700 cyc of cover vs ~250 in r6).
__global__ __launch_bounds__(256, 4)
void vq_main(const float* __restrict__ in,
             const float* __restrict__ cb,
             const _Float16* __restrict__ w,
             const float* __restrict__ wesq,
             float* __restrict__ out) {
    __shared__ __align__(16) _Float16 bt[2][4][2048];  // 2 bufs x 4 tiles x 4 KB = 32 KB
    __shared__ float esq_s[K_CODES];                   // 4 KB
    __shared__ int   idx_s[128];

    const int tid  = threadIdx.x;
    const int wave = tid >> 6;
    const int lane = tid & 63;
    const int lo4  = lane & 15;   // code residue (C col) / token residue (A m)
    const int quad = lane >> 4;   // k-octet selector in A/B frags; token-row group in C

    // stage e_sq table into LDS once (16 distinct words/read later -> broadcast, free)
    for (int k = tid; k < K_CODES; k += 256) esq_s[k] = wesq[k];

    const int strip = blockIdx.x * 128 + wave * 32;   // 32 tokens per wave
    const int b  = strip >> 13;
    const int t0 = strip & 8191;

    // ---- A fragments: -2 * X[token][d] -> f16 hi/lo (layout HW-verified r2-r6) ----
    const float* xin = in + (size_t)b * DIM * T_LEN + t0;
    half8 a_hi[2][2], a_lo[2][2];
    #pragma unroll
    for (int mt = 0; mt < 2; ++mt) {
        #pragma unroll
        for (int s = 0; s < 2; ++s) {
            half8 hh, ll;
            #pragma unroll
            for (int j = 0; j < 8; ++j) {
                const int d = s * 32 + quad * 8 + j;
                float xv = -2.0f * xin[(size_t)d * T_LEN + mt * 16 + lo4];
                _Float16 h = (_Float16)xv;
                hh[j] = h;
                ll[j] = (_Float16)((xv - (float)h) * LO_SCALE);
            }
            a_hi[mt][s] = hh;
            a_lo[mt][s] = ll;
        }
    }

    float best[8];
    int   bidx[8];
    #pragma unroll
    for (int i = 0; i < 8; ++i) { best[i] = FLT_MAX; bidx[i] = 0; }

    // stage period `per` (tiles 4per..4per+3, 16 KB) into bt[buf]; 16 chunks of 1 KB,
    // wave W issues chunks {W, W+4, W+8, W+12} (chunk index wave-uniform).
    const char* wbytes = (const char*)w;
    auto stage = [&](int per, int buf) {
        const char* src = wbytes + (size_t)per * 16384 + lane * 16;
        char* dst = (char*)&bt[buf][0][0] + lane * 16;
        #pragma unroll
        for (int i = 0; i < 4; ++i) {
            const int c = (wave + i * 4) * 1024;
            async_16B(src + c, dst + c);
        }
    };

    stage(0, 0);
    __syncthreads();   // drains vmcnt: buf 0 + esq_s ready

    for (int per = 0; per < 16; ++per) {
        const int buf = per & 1;
        if (per < 15) stage(per + 1, buf ^ 1);   // in flight during this period's compute
        #pragma unroll
        for (int j = 0; j < 4; ++j) {
            const int ct = per * 4 + j;
            const _Float16* tp = &bt[buf][j][lane * 8];
            half8 h0 = *reinterpret_cast<const half8*>(tp);          // hi, k 0..31
            half8 h1 = *reinterpret_cast<const half8*>(tp + 512);    // hi, k 32..63
            half8 l0 = *reinterpret_cast<const half8*>(tp + 1024);   // lo, k 0..31
            half8 l1 = *reinterpret_cast<const half8*>(tp + 1536);   // lo, k 32..63
            const float es = esq_s[ct * 16 + lo4];
            const int code = ct * 16 + lo4;
            #pragma unroll
            for (int mt = 0; mt < 2; ++mt) {
                f32x4 c1 = {es, es, es, es};    // ||e||^2 folded into C input
                f32x4 c2 = {0.f, 0.f, 0.f, 0.f};
                c1 = MFMA16(a_hi[mt][0], h0, c1);
                c1 = MFMA16(a_hi[mt][1], h1, c1);
                c2 = MFMA16(a_lo[mt][0], h0, c2);
                c2 = MFMA16(a_lo[mt][1], h1, c2);
                c2 = MFMA16(a_hi[mt][0], l0, c2);
                c2 = MFMA16(a_hi[mt][1], l1, c2);
                #pragma unroll
                for (int r = 0; r < 4; ++r) {
                    float sc = fmaf(c2[r], LO_INV, c1[r]);  // ||e||^2 - 2 x.e
                    const int i = mt * 4 + r;
                    bool lt = sc < best[i];                  // strict <: first occurrence
                    best[i] = lt ? sc : best[i];
                    bidx[i] = lt ? code : bidx[i];
                }
            }
        }
        __syncthreads();   // all waves done with buf; next buf's loads drained
    }

    // ---- cross-lane merge over the 16 code-residue lanes ----
    #pragma unroll
    for (int i = 0; i < 8; ++i) {
        float s = best[i];
        int  ix = bidx[i];
        #pragma unroll
        for (int off = 1; off < 16; off <<= 1) {
            float s2 = __shfl_xor(s, off, 64);
            int  ix2 = __shfl_xor(ix, off, 64);
            bool take = (s2 < s) || (s2 == s && ix2 < ix);  // tie -> lower index
            s  = take ? s2 : s;
            ix = take ? ix2 : ix;
        }
        if (lo4 == 0) {
            // token_local = mt*16 + quad*4 + r,  mt = i>>2, r = i&3
            idx_s[wave * 32 + (i >> 2) * 16 + quad * 4 + (i & 3)] = ix;
        }
    }
    __syncthreads();

    // ---- epilogue: 2 threads per token (32 dims each), gather + coalesced store ----
    const int tok_local = tid & 127;
    const int dhalf = tid >> 7;
    const int token = blockIdx.x * 128 + tok_local;
    const int tb = token >> 13;
    const int tt = token & 8191;
    const int my_idx = idx_s[tok_local];

    if (dhalf == 0)
        out[(size_t)N_TOK * DIM + token] = (float)my_idx;   // index output

    const float* crow = cb + (size_t)my_idx * DIM + dhalf * 32;
    float* outv = out + (size_t)tb * DIM * T_LEN + (size_t)(dhalf * 32) * T_LEN + tt;
    #pragma unroll
    for (int d0 = 0; d0 < 32; d0 += 4) {
        float4 v = *reinterpret_cast<const float4*>(crow + d0);  // L2-hot gather
        outv[(size_t)(d0 + 0) * T_LEN] = v.x;
        outv[(size_t)(d0 + 1) * T_LEN] = v.y;
        outv[(size_t)(d0 + 2) * T_LEN] = v.z;
        outv[(size_t)(d0 + 3) * T_LEN] = v.w;
    }
}

extern "C" void kernel_launch(void* const* d_in, const int* in_sizes, int n_in,
                              void* d_out, int out_size, void* d_ws, size_t ws_size,
                              hipStream_t stream) {
    const float* in = (const float*)d_in[0];   // (16, 64, 8192) fp32
    const float* cb = (const float*)d_in[1];   // (1024, 64) fp32
    float* out = (float*)d_out;

    _Float16* w   = (_Float16*)d_ws;                       // 64 tiles * 4 KB = 256 KB
    float*   wesq = (float*)((char*)d_ws + 64 * 4096);     // 4 KB

    vq_prep<<<dim3(64), dim3(256), 0, stream>>>(cb, w, wesq);
    vq_main<<<dim3(N_TOK / 128), dim3(256), 0, stream>>>(in, cb, w, wesq, out);
}